// Round 1
// baseline (304.201 us; speedup 1.0000x reference)
//
#include <hip/hip_runtime.h>
#include <math.h>

// ---------------------------------------------------------------------------
// Fused 11-layer funnel MLP (15->30->60->90->120->90->60->30->15->10->5->1)
// bf16 MFMA (16x16x32), fp32 accumulate, fused ReLU / bias / sigmoid.
// Persistent blocks: weights staged to LDS once per block, activations ping-
// pong in wave-private LDS buffers (no barriers in the main loop).
// LDS: 86KB weights (bf16, zero-padded [N_pad][K_pad]) + 2.25KB fp32 bias
//      + 8 waves * 2 * [16][128] bf16 activation buffers = 152 KB (dynamic).
// ---------------------------------------------------------------------------

using bf16x8 = __attribute__((ext_vector_type(8))) short;   // 8 bf16 = 4 VGPRs
using f32x4  = __attribute__((ext_vector_type(4))) float;

namespace {
constexpr int NL = 11;
constexpr int IN_[NL]   = {15, 30, 60, 90, 120, 90, 60, 30, 15, 10, 5};
constexpr int OUT_[NL]  = {30, 60, 90, 120, 90, 60, 30, 15, 10, 5, 1};
constexpr int KP_[NL]   = {32, 32, 64, 96, 128, 96, 64, 32, 32, 32, 32};  // in, padded to 32
constexpr int NP_[NL]   = {32, 64, 96, 128, 96, 64, 32, 16, 16, 16, 16};  // out, padded to 16
// cumulative offsets (elements) of each layer's [NP][KP] bf16 weight block
constexpr int WOFF_[NL] = {0, 1024, 3072, 9216, 21504, 33792, 39936, 41984, 42496, 43008, 43520};
constexpr int WTOT      = 44032;   // shorts
constexpr int BOFF_[NL] = {0, 32, 96, 192, 320, 416, 480, 512, 528, 544, 560};
constexpr int BTOT      = 576;     // floats
constexpr int ACT_OFF   = (WTOT * 2 + BTOT * 4) / 2;   // short index 45184 (16B aligned)
constexpr int WAVES     = 8;
constexpr int ROWS_PER_BLOCK = WAVES * 16;             // 128
constexpr int LDS_BYTES = WTOT * 2 + BTOT * 4 + WAVES * 2 * 2048 * 2;  // 155904
}

// fp32 -> bf16, round-to-nearest-even (finite inputs only)
__device__ __forceinline__ short f2bf(float f) {
    unsigned u = __float_as_uint(f);
    u += 0x7fffu + ((u >> 16) & 1u);
    return (short)(u >> 16);
}

template <int L>
__device__ __forceinline__ void stage_w(const float* __restrict__ W,
                                        const float* __restrict__ B,
                                        short* wlds, float* blds, int tid) {
    constexpr int KP = KP_[L], NP = NP_[L], INl = IN_[L], OUTl = OUT_[L];
    for (int idx = tid; idx < NP * KP; idx += 512) {
        int n = idx / KP;            // KP is a compile-time constant -> magic mul
        int k = idx - n * KP;
        float v = (n < OUTl && k < INl) ? W[n * INl + k] : 0.f;
        wlds[WOFF_[L] + idx] = f2bf(v);
    }
    for (int idx = tid; idx < NP; idx += 512)
        blds[BOFF_[L] + idx] = (idx < OUTl) ? B[idx] : 0.f;
}

// One Linear+ReLU layer for this wave's 16-row tile: cur [16][KP] -> nxt [16][KPN]
template <int L>
__device__ __forceinline__ void layer_fwd(const short* __restrict__ wlds,
                                          const float* __restrict__ blds,
                                          const short* cur, short* nxt, int lane) {
    constexpr int KP  = KP_[L];
    constexpr int NP  = NP_[L];
    constexpr int KPN = (L < NL - 1) ? KP_[L + 1] : 32;   // width of next activation buffer
    const int col  = lane & 15;    // A/B free index within a 16-tile
    const int quad = lane >> 4;

    // A fragments: A[m = col][k = kt*32 + quad*8 + j]  (m118/m120-verified layout)
    bf16x8 af[KP / 32];
#pragma unroll
    for (int kt = 0; kt < KP / 32; ++kt)
        af[kt] = *(const bf16x8*)(cur + col * KP + kt * 32 + quad * 8);

#pragma unroll
    for (int nt = 0; nt < NP / 16; ++nt) {
        f32x4 acc = {0.f, 0.f, 0.f, 0.f};
#pragma unroll
        for (int kt = 0; kt < KP / 32; ++kt) {
            // B fragment: lane holds B[k = kt*32 + quad*8 + j][n = nt*16 + col]
            // with B[k][n] := W[n][k]  ->  contiguous k from row n of W_pad
            bf16x8 bf = *(const bf16x8*)(wlds + WOFF_[L] + (nt * 16 + col) * KP + kt * 32 + quad * 8);
            acc = __builtin_amdgcn_mfma_f32_16x16x32_bf16(af[kt], bf, acc, 0, 0, 0);
        }
        // C/D layout: col = lane&15 (n), row = quad*4 + r (m)   (m89/m91-verified)
        const int n = nt * 16 + col;
        const float bias = blds[BOFF_[L] + n];
#pragma unroll
        for (int r = 0; r < 4; ++r) {
            float v = acc[r] + bias;
            v = fmaxf(v, 0.f);
            nxt[(quad * 4 + r) * KPN + n] = f2bf(v);
        }
    }
    // Layers whose padded OUT (16) is narrower than the next K padding (32):
    // zero cols [NP, KPN) so pad region is 0, never stale LDS garbage/NaN.
    if constexpr (NP < KPN) {
#pragma unroll
        for (int r = 0; r < 4; ++r)
            nxt[(quad * 4 + r) * KPN + NP + col] = 0;
    }
}

extern "C" __global__ void __launch_bounds__(512, 2)
mlp_fused(const float* __restrict__ x,
          const float* __restrict__ W0,  const float* __restrict__ B0,
          const float* __restrict__ W1,  const float* __restrict__ B1,
          const float* __restrict__ W2,  const float* __restrict__ B2,
          const float* __restrict__ W3,  const float* __restrict__ B3,
          const float* __restrict__ W4,  const float* __restrict__ B4,
          const float* __restrict__ W5,  const float* __restrict__ B5,
          const float* __restrict__ W6,  const float* __restrict__ B6,
          const float* __restrict__ W7,  const float* __restrict__ B7,
          const float* __restrict__ W8,  const float* __restrict__ B8,
          const float* __restrict__ W9,  const float* __restrict__ B9,
          const float* __restrict__ W10, const float* __restrict__ B10,
          float* __restrict__ out, int nrows, int nchunks) {
    extern __shared__ short smem[];
    short* wlds = smem;
    float* blds = (float*)(smem + WTOT);
    short* act  = smem + ACT_OFF;

    const int tid = threadIdx.x;

    // ---- stage all weights/biases into LDS once per (persistent) block ----
    stage_w<0>(W0, B0, wlds, blds, tid);
    stage_w<1>(W1, B1, wlds, blds, tid);
    stage_w<2>(W2, B2, wlds, blds, tid);
    stage_w<3>(W3, B3, wlds, blds, tid);
    stage_w<4>(W4, B4, wlds, blds, tid);
    stage_w<5>(W5, B5, wlds, blds, tid);
    stage_w<6>(W6, B6, wlds, blds, tid);
    stage_w<7>(W7, B7, wlds, blds, tid);
    stage_w<8>(W8, B8, wlds, blds, tid);
    stage_w<9>(W9, B9, wlds, blds, tid);
    stage_w<10>(W10, B10, wlds, blds, tid);
    __syncthreads();

    const int wave = tid >> 6;
    const int lane = tid & 63;
    const int col  = lane & 15;
    const int quad = lane >> 4;
    short* buf0 = act + wave * 4096;   // [16][128] bf16
    short* buf1 = buf0 + 2048;

    for (int chunk = blockIdx.x; chunk < nchunks; chunk += gridDim.x) {
        const int row0 = chunk * ROWS_PER_BLOCK + wave * 16;

        // ---- stage this wave's 16 rows of x into buf0 as [16][32] bf16 ----
#pragma unroll
        for (int i = 0; i < 8; ++i) {
            int idx = lane + i * 64;
            int r = idx >> 5, c = idx & 31;
            float v = 0.f;
            if (c < 15) v = x[(row0 + r) * 15 + c];
            buf0[idx] = f2bf(v);
        }

        layer_fwd<0>(wlds, blds, buf0, buf1, lane);
        layer_fwd<1>(wlds, blds, buf1, buf0, lane);
        layer_fwd<2>(wlds, blds, buf0, buf1, lane);
        layer_fwd<3>(wlds, blds, buf1, buf0, lane);
        layer_fwd<4>(wlds, blds, buf0, buf1, lane);
        layer_fwd<5>(wlds, blds, buf1, buf0, lane);
        layer_fwd<6>(wlds, blds, buf0, buf1, lane);
        layer_fwd<7>(wlds, blds, buf1, buf0, lane);
        layer_fwd<8>(wlds, blds, buf0, buf1, lane);
        layer_fwd<9>(wlds, blds, buf1, buf0, lane);

        // ---- final layer (5 -> 1) + sigmoid, input in buf0 [16][32] ----
        {
            bf16x8 a = *(const bf16x8*)(buf0 + col * 32 + quad * 8);
            bf16x8 b = *(const bf16x8*)(wlds + WOFF_[10] + col * 32 + quad * 8);
            f32x4 acc = {0.f, 0.f, 0.f, 0.f};
            acc = __builtin_amdgcn_mfma_f32_16x16x32_bf16(a, b, acc, 0, 0, 0);
            if (col == 0) {   // lanes holding n == 0 (the only real output)
                const float bias = blds[BOFF_[10]];
                float4 o;
                o.x = 1.f / (1.f + expf(-(acc[0] + bias)));
                o.y = 1.f / (1.f + expf(-(acc[1] + bias)));
                o.z = 1.f / (1.f + expf(-(acc[2] + bias)));
                o.w = 1.f / (1.f + expf(-(acc[3] + bias)));
                *(float4*)(out + row0 + quad * 4) = o;
            }
        }
    }
}

extern "C" void kernel_launch(void* const* d_in, const int* in_sizes, int n_in,
                              void* d_out, int out_size, void* d_ws, size_t ws_size,
                              hipStream_t stream) {
    (void)n_in; (void)d_ws; (void)ws_size;
    const float* x = (const float*)d_in[0];
    const float* W[11];
    const float* B[11];
    for (int i = 0; i < 11; ++i) {
        W[i] = (const float*)d_in[1 + 2 * i];
        B[i] = (const float*)d_in[2 + 2 * i];
    }
    const int nrows   = in_sizes[0] / 15;
    const int nchunks = nrows / ROWS_PER_BLOCK;   // 524288/128 = 4096

    // MI355X has 160 KiB LDS/CU; opt in to >64 KiB dynamic shared.
    hipFuncSetAttribute((const void*)mlp_fused,
                        hipFuncAttributeMaxDynamicSharedMemorySize, LDS_BYTES);

    mlp_fused<<<dim3(512), dim3(512), LDS_BYTES, stream>>>(
        x,
        W[0], B[0], W[1], B[1], W[2], B[2], W[3], B[3], W[4], B[4],
        W[5], B[5], W[6], B[6], W[7], B[7], W[8], B[8], W[9], B[9],
        W[10], B[10],
        (float*)d_out, nrows, nchunks);
}

// Round 2
// 198.381 us; speedup vs baseline: 1.5334x; 1.5334x over previous
//
#include <hip/hip_runtime.h>
#include <math.h>

// ---------------------------------------------------------------------------
// Fused 11-layer funnel MLP, round 2: conflict-free fragment-major LDS.
// Orientation D = W·h^T:  A = weight tile (m=out,k=in), B = activations
// (k=in, n=batch row). All LDS accesses are lane*16B (conflict-free b128)
// or 8B paired (2-way = free). Epilogue writes C-layout directly into the
// next layer's B-frag layout as one ds_write_b64 per tile. Activations live
// in a single in-place 8KB/wave arena (B-frags register-preloaded per layer)
// so each wave processes 32 rows per pass. No barriers in the main loop.
// ---------------------------------------------------------------------------

using bf16x8 = __attribute__((ext_vector_type(8))) short;   // 8 bf16 = 4 VGPRs
using f32x4  = __attribute__((ext_vector_type(4))) float;
using u16x4  = __attribute__((ext_vector_type(4))) unsigned short;
using u16x8  = __attribute__((ext_vector_type(8))) unsigned short;

namespace {
constexpr int NL = 11;
constexpr int IN_[NL]   = {15, 30, 60, 90, 120, 90, 60, 30, 15, 10, 5};
constexpr int OUT_[NL]  = {30, 60, 90, 120, 90, 60, 30, 15, 10, 5, 1};
constexpr int KP_[NL]   = {32, 32, 64, 96, 128, 96, 64, 32, 32, 32, 32};  // in, pad 32
constexpr int NP_[NL]   = {32, 64, 96, 128, 96, 64, 32, 16, 16, 16, 16};  // out, pad 16
constexpr int WOFF_[NL] = {0, 1024, 3072, 9216, 21504, 33792, 39936, 41984, 42496, 43008, 43520};
constexpr int WTOT      = 44032;   // shorts
constexpr int BOFF_[NL] = {0, 32, 96, 192, 320, 416, 480, 512, 528, 544, 560};
constexpr int BTOT      = 576;     // floats
constexpr int ACT_OFF   = (WTOT * 2 + BTOT * 4) / 2;   // short index 45184
constexpr int WAVES     = 8;
constexpr int ROWS_PER_WAVE  = 32;
constexpr int ROWS_PER_BLOCK = WAVES * ROWS_PER_WAVE;  // 256
constexpr int ARENA     = 4096;    // shorts per wave (8 KB)
constexpr int LDS_BYTES = WTOT * 2 + BTOT * 4 + WAVES * ARENA * 2;  // 155904
}

// fp32 -> bf16, round-to-nearest-even (finite inputs only)
__device__ __forceinline__ unsigned short f2bf(float f) {
    unsigned u = __float_as_uint(f);
    u += 0x7fffu + ((u >> 16) & 1u);
    return (unsigned short)(u >> 16);
}

// Stage layer L's weights into LDS in A-frag-major order:
// frag f = mt*(KP/32)+kt holds tile (m = mt*16+col, k = kt*32+quad*8+j) at
// short offset f*512 + quad*128 + col*8 + j  -> reads are lane*16B.
template <int L>
__device__ __forceinline__ void stage_w(const float* __restrict__ W,
                                        const float* __restrict__ B,
                                        short* wlds, float* blds, int tid) {
    constexpr int KP = KP_[L], NP = NP_[L], INl = IN_[L], OUTl = OUT_[L];
    constexpr int NKT = KP / 32;
    for (int idx = tid; idx < NP * KP; idx += 512) {
        const int f    = idx >> 9;
        const int t    = idx & 511;
        const int quad = t >> 7;
        const int col  = (t >> 3) & 15;
        const int j    = t & 7;
        const int mt   = f / NKT;
        const int kt   = f - mt * NKT;
        const int m    = mt * 16 + col;
        const int k    = kt * 32 + quad * 8 + j;
        float v = (m < OUTl && k < INl) ? W[m * INl + k] : 0.f;
        wlds[WOFF_[L] + idx] = (short)f2bf(v);
    }
    for (int idx = tid; idx < NP; idx += 512)
        blds[BOFF_[L] + idx] = (idx < OUTl) ? B[idx] : 0.f;
}

// One Linear+ReLU layer over this wave's 32 rows, in place in `buf`.
// Input:  B-frag-major blocks (b*NKT + kt)*512, b in {0,1} (rows b*16+col).
// Output: B-frag-major for the next layer (block stride NKTN).
template <int L>
__device__ __forceinline__ void layer_fwd(const short* __restrict__ wlds,
                                          const float* __restrict__ blds,
                                          short* buf, int col, int quad) {
    constexpr int KP   = KP_[L];
    constexpr int NP   = NP_[L];
    constexpr int NKT  = KP / 32;
    constexpr int NMT  = NP / 16;
    constexpr int KPN  = KP_[L + 1];   // instantiated only for L <= 9
    constexpr int NKTN = KPN / 32;

    // Preload all B-frags (activations) for both row-tiles -> buf is dead.
    bf16x8 bfr[2][NKT];
#pragma unroll
    for (int b = 0; b < 2; ++b)
#pragma unroll
        for (int kt = 0; kt < NKT; ++kt)
            bfr[b][kt] = *(const bf16x8*)(buf + (b * NKT + kt) * 512 + quad * 128 + col * 8);

#pragma unroll
    for (int mt = 0; mt < NMT; ++mt) {
        f32x4 acc0 = {0.f, 0.f, 0.f, 0.f};
        f32x4 acc1 = {0.f, 0.f, 0.f, 0.f};
#pragma unroll
        for (int kt = 0; kt < NKT; ++kt) {
            bf16x8 af = *(const bf16x8*)(wlds + WOFF_[L] + (mt * NKT + kt) * 512 + quad * 128 + col * 8);
            acc0 = __builtin_amdgcn_mfma_f32_16x16x32_bf16(af, bfr[0][kt], acc0, 0, 0, 0);
            acc1 = __builtin_amdgcn_mfma_f32_16x16x32_bf16(af, bfr[1][kt], acc1, 0, 0, 0);
        }
        // bias[m], m = mt*16 + quad*4 + r : one b128 per mt (quad-broadcast)
        f32x4 bias = *(const f32x4*)(blds + BOFF_[L] + mt * 16 + quad * 4);
        // C layout (m=quad*4+r, n=col) -> next-layer B-frag slot: 4 consecutive
        // shorts at block (b*NKTN + mt/2), quad_c=(mt&1)*2+(quad>>1), j0=(quad&1)*4
        const int wbase = (mt >> 1) * 512 + ((mt & 1) * 2 + (quad >> 1)) * 128 + col * 8 + (quad & 1) * 4;
#pragma unroll
        for (int b = 0; b < 2; ++b) {
            u16x4 o;
#pragma unroll
            for (int r = 0; r < 4; ++r) {
                float v = (b ? acc1[r] : acc0[r]) + bias[r];
                v = fmaxf(v, 0.f);
                o[r] = f2bf(v);
            }
            *(u16x4*)(buf + b * NKTN * 512 + wbase) = o;
        }
    }
    // Layers with padded OUT (16) < next K pad (32): zero k in [16,32).
    if constexpr (NP < KPN) {
        u16x8 z = {0, 0, 0, 0, 0, 0, 0, 0};
        *(u16x8*)(buf + (quad >> 1) * NKTN * 512 + (2 + (quad & 1)) * 128 + col * 8) = z;
    }
}

extern "C" __global__ void __launch_bounds__(512, 1)
mlp_fused(const float* __restrict__ x,
          const float* __restrict__ W0,  const float* __restrict__ B0,
          const float* __restrict__ W1,  const float* __restrict__ B1,
          const float* __restrict__ W2,  const float* __restrict__ B2,
          const float* __restrict__ W3,  const float* __restrict__ B3,
          const float* __restrict__ W4,  const float* __restrict__ B4,
          const float* __restrict__ W5,  const float* __restrict__ B5,
          const float* __restrict__ W6,  const float* __restrict__ B6,
          const float* __restrict__ W7,  const float* __restrict__ B7,
          const float* __restrict__ W8,  const float* __restrict__ B8,
          const float* __restrict__ W9,  const float* __restrict__ B9,
          const float* __restrict__ W10, const float* __restrict__ B10,
          float* __restrict__ out, int nchunks) {
    extern __shared__ short smem[];
    short* wlds = smem;
    float* blds = (float*)(smem + WTOT);
    short* act  = smem + ACT_OFF;

    const int tid = threadIdx.x;

    stage_w<0>(W0, B0, wlds, blds, tid);
    stage_w<1>(W1, B1, wlds, blds, tid);
    stage_w<2>(W2, B2, wlds, blds, tid);
    stage_w<3>(W3, B3, wlds, blds, tid);
    stage_w<4>(W4, B4, wlds, blds, tid);
    stage_w<5>(W5, B5, wlds, blds, tid);
    stage_w<6>(W6, B6, wlds, blds, tid);
    stage_w<7>(W7, B7, wlds, blds, tid);
    stage_w<8>(W8, B8, wlds, blds, tid);
    stage_w<9>(W9, B9, wlds, blds, tid);
    stage_w<10>(W10, B10, wlds, blds, tid);
    __syncthreads();

    const int wave = tid >> 6;
    const int lane = tid & 63;
    const int col  = lane & 15;
    const int quad = lane >> 4;
    short* buf = act + wave * ARENA;

    for (int chunk = blockIdx.x; chunk < nchunks; chunk += gridDim.x) {
        const int row0 = chunk * ROWS_PER_BLOCK + wave * ROWS_PER_WAVE;

        // ---- stage 32 rows of x into B-frag layout (KP=32, blocks b=0,1) ----
#pragma unroll
        for (int b = 0; b < 2; ++b) {
            const int row = row0 + b * 16 + col;
            const float* xr = x + (long)row * 15;
            float v[4];
            if (quad < 3) {
                float4 t;
                __builtin_memcpy(&t, xr + quad * 4, 16);
                v[0] = t.x; v[1] = t.y; v[2] = t.z; v[3] = t.w;
            } else {
                v[0] = xr[12]; v[1] = xr[13]; v[2] = xr[14]; v[3] = 0.f;
            }
            u16x4 o;
#pragma unroll
            for (int r = 0; r < 4; ++r) o[r] = f2bf(v[r]);
            *(u16x4*)(buf + b * 512 + (quad >> 1) * 128 + col * 8 + (quad & 1) * 4) = o;
        }
        {   // zero k in [16,32) for both row-tiles
            u16x8 z = {0, 0, 0, 0, 0, 0, 0, 0};
            *(u16x8*)(buf + (quad >> 1) * 512 + (2 + (quad & 1)) * 128 + col * 8) = z;
        }

        layer_fwd<0>(wlds, blds, buf, col, quad);
        layer_fwd<1>(wlds, blds, buf, col, quad);
        layer_fwd<2>(wlds, blds, buf, col, quad);
        layer_fwd<3>(wlds, blds, buf, col, quad);
        layer_fwd<4>(wlds, blds, buf, col, quad);
        layer_fwd<5>(wlds, blds, buf, col, quad);
        layer_fwd<6>(wlds, blds, buf, col, quad);
        layer_fwd<7>(wlds, blds, buf, col, quad);
        layer_fwd<8>(wlds, blds, buf, col, quad);
        layer_fwd<9>(wlds, blds, buf, col, quad);

        // ---- final layer (5 -> 1, padded 32 -> 16) + sigmoid ----
        {
            bf16x8 af = *(const bf16x8*)(wlds + WOFF_[10] + quad * 128 + col * 8);
            bf16x8 b0 = *(const bf16x8*)(buf + quad * 128 + col * 8);
            bf16x8 b1 = *(const bf16x8*)(buf + 512 + quad * 128 + col * 8);
            f32x4 acc0 = {0.f, 0.f, 0.f, 0.f};
            f32x4 acc1 = {0.f, 0.f, 0.f, 0.f};
            acc0 = __builtin_amdgcn_mfma_f32_16x16x32_bf16(af, b0, acc0, 0, 0, 0);
            acc1 = __builtin_amdgcn_mfma_f32_16x16x32_bf16(af, b1, acc1, 0, 0, 0);
            if (quad == 0) {   // rows m = 0..3; only m==0 (r=0) is real
                const float bias0 = blds[BOFF_[10]];
                const float z0 = acc0[0] + bias0;
                const float z1 = acc1[0] + bias0;
                out[row0 + col]      = 1.f / (1.f + __expf(-z0));
                out[row0 + 16 + col] = 1.f / (1.f + __expf(-z1));
            }
        }
    }
}

extern "C" void kernel_launch(void* const* d_in, const int* in_sizes, int n_in,
                              void* d_out, int out_size, void* d_ws, size_t ws_size,
                              hipStream_t stream) {
    (void)n_in; (void)d_ws; (void)ws_size; (void)out_size;
    const float* x = (const float*)d_in[0];
    const float* W[11];
    const float* B[11];
    for (int i = 0; i < 11; ++i) {
        W[i] = (const float*)d_in[1 + 2 * i];
        B[i] = (const float*)d_in[2 + 2 * i];
    }
    const int nrows   = in_sizes[0] / 15;
    const int nchunks = nrows / ROWS_PER_BLOCK;   // 524288/256 = 2048

    hipFuncSetAttribute((const void*)mlp_fused,
                        hipFuncAttributeMaxDynamicSharedMemorySize, LDS_BYTES);

    mlp_fused<<<dim3(256), dim3(512), LDS_BYTES, stream>>>(
        x,
        W[0], B[0], W[1], B[1], W[2], B[2], W[3], B[3], W[4], B[4],
        W[5], B[5], W[6], B[6], W[7], B[7], W[8], B[8], W[9], B[9],
        W[10], B[10],
        (float*)d_out, nchunks);
}

// Round 3
// 196.844 us; speedup vs baseline: 1.5454x; 1.0078x over previous
//
#include <hip/hip_runtime.h>
#include <math.h>

// ---------------------------------------------------------------------------
// Fused 11-layer funnel MLP, round 3.
// - Fragment-major conflict-free LDS (round 2) retained.
// - Bias folded into MFMA via pad columns: W_pad[m][IN]=bias_hi,
//   W_pad[m][IN+1]=bias_lo; pad rows m=OUT,OUT+1 emit constant 1.0 through
//   ReLU so the next layer's bias columns see activation 1.0. Epilogue is
//   now just ReLU + packed bf16 convert.
// - v_cvt_pk_bf16_f32 (gfx950) for 2-elem/instr fp32->bf16.
// - k-outer loop with all accumulators live (ILP), launch_bounds(512,2).
// - Tail-layer weight frags preloaded to VGPRs; x prefetched across layers.
// ---------------------------------------------------------------------------

using bf16x8 = __attribute__((ext_vector_type(8))) short;   // 8 bf16 = 4 VGPRs
using f32x4  = __attribute__((ext_vector_type(4))) float;
using u16x8  = __attribute__((ext_vector_type(8))) unsigned short;
using u32x2  = __attribute__((ext_vector_type(2))) unsigned;
typedef __bf16 bf16x2_t __attribute__((ext_vector_type(2)));

namespace {
constexpr int NL = 11;
constexpr int IN_[NL]   = {15, 30, 60, 90, 120, 90, 60, 30, 15, 10, 5};
constexpr int OUT_[NL]  = {30, 60, 90, 120, 90, 60, 30, 15, 10, 5, 1};
constexpr int KP_[NL]   = {32, 32, 64, 96, 128, 96, 64, 32, 32, 32, 32};  // in, pad 32
constexpr int NP_[NL]   = {32, 64, 96, 128, 96, 64, 32, 16, 16, 16, 16};  // out, pad 16
constexpr int WOFF_[NL] = {0, 1024, 3072, 9216, 21504, 33792, 39936, 41984, 42496, 43008, 43520};
constexpr int WTOT      = 44032;   // shorts
constexpr int ACT_OFF   = WTOT;
constexpr int WAVES     = 8;
constexpr int ROWS_PER_BLOCK = WAVES * 32;            // 256
constexpr int ARENA     = 4096;    // shorts per wave (8 KB)
constexpr int LDS_BYTES = (WTOT + WAVES * ARENA) * 2; // 153600
}

// fp32 -> bf16 RNE (scalar, staging only)
__device__ __forceinline__ unsigned short f2bf(float f) {
    unsigned u = __float_as_uint(f);
    u += 0x7fffu + ((u >> 16) & 1u);
    return (unsigned short)(u >> 16);
}

// packed fp32x2 -> bf16x2 (RNE); gfx950 has v_cvt_pk_bf16_f32
__device__ __forceinline__ unsigned pk2(float a, float b) {
#if __has_builtin(__builtin_amdgcn_cvt_pk_bf16_f32)
    return __builtin_bit_cast(unsigned, __builtin_amdgcn_cvt_pk_bf16_f32(a, b));
#else
    bf16x2_t c;
    c[0] = (__bf16)a;
    c[1] = (__bf16)b;
    return __builtin_bit_cast(unsigned, c);
#endif
}

// Stage layer L's weights (A-frag-major) with bias/one-hot pads folded in.
template <int L>
__device__ __forceinline__ void stage_w(const float* __restrict__ W,
                                        const float* __restrict__ B,
                                        short* wlds, int tid) {
    constexpr int KP = KP_[L], NP = NP_[L], INl = IN_[L], OUTl = OUT_[L];
    constexpr int NKT = KP / 32;
    for (int idx = tid; idx < NP * KP; idx += 512) {
        const int f    = idx >> 9;
        const int t    = idx & 511;
        const int quad = t >> 7;
        const int colc = (t >> 3) & 15;
        const int j    = t & 7;
        const int mt   = f / NKT;
        const int kt   = f - mt * NKT;
        const int m    = mt * 16 + colc;
        const int k    = kt * 32 + quad * 8 + j;
        float v = 0.f;
        if (m < OUTl) {
            if (k < INl) v = W[m * INl + k];
            else if (k == INl) v = B[m];                    // f2bf -> bias_hi
            else if (k == INl + 1) {                        // bias_lo
                float hf = __builtin_bit_cast(float, (unsigned)f2bf(B[m]) << 16);
                v = B[m] - hf;
            }
        } else if (m == OUTl || m == OUTl + 1) {
            if (k == INl) v = 1.f;                          // 1.0-generator row
        }
        wlds[WOFF_[L] + idx] = (short)f2bf(v);
    }
}

// One Linear+ReLU layer over this wave's 32 rows, in place in `buf`.
// k-outer, all 2*NMT accumulator chains live.
template <int L>
__device__ __forceinline__ void layer_fwd(const short* __restrict__ wlds,
                                          short* buf, int col, int quad) {
    constexpr int KP   = KP_[L];
    constexpr int NP   = NP_[L];
    constexpr int NKT  = KP / 32;
    constexpr int NMT  = NP / 16;
    constexpr int KPN  = KP_[L + 1];
    constexpr int NKTN = KPN / 32;
    const short* wl = wlds + WOFF_[L];
    const int fo = quad * 128 + col * 8;

    f32x4 acc[NMT][2];
#pragma unroll
    for (int mt = 0; mt < NMT; ++mt)
#pragma unroll
        for (int b = 0; b < 2; ++b)
            acc[mt][b] = f32x4{0.f, 0.f, 0.f, 0.f};

#pragma unroll
    for (int kt = 0; kt < NKT; ++kt) {
        bf16x8 b0 = *(const bf16x8*)(buf + kt * 512 + fo);
        bf16x8 b1 = *(const bf16x8*)(buf + (NKT + kt) * 512 + fo);
#pragma unroll
        for (int mt = 0; mt < NMT; ++mt) {
            bf16x8 af = *(const bf16x8*)(wl + (mt * NKT + kt) * 512 + fo);
            acc[mt][0] = __builtin_amdgcn_mfma_f32_16x16x32_bf16(af, b0, acc[mt][0], 0, 0, 0);
            acc[mt][1] = __builtin_amdgcn_mfma_f32_16x16x32_bf16(af, b1, acc[mt][1], 0, 0, 0);
        }
    }
#pragma unroll
    for (int mt = 0; mt < NMT; ++mt) {
        const int wbase = (mt >> 1) * 512 + ((mt & 1) * 2 + (quad >> 1)) * 128 + col * 8 + (quad & 1) * 4;
#pragma unroll
        for (int b = 0; b < 2; ++b) {
            u32x2 o;
            o[0] = pk2(fmaxf(acc[mt][b][0], 0.f), fmaxf(acc[mt][b][1], 0.f));
            o[1] = pk2(fmaxf(acc[mt][b][2], 0.f), fmaxf(acc[mt][b][3], 0.f));
            *(u32x2*)(buf + b * NKTN * 512 + wbase) = o;
        }
    }
    // NP(16) < KPN(32): fill k in [16,32) with 0, except k==16 := 1.0
    if constexpr (NP < KPN) {
        u16x8 z = {0, 0, 0, 0, 0, 0, 0, 0};
        if ((quad & 1) == 0) z[0] = (unsigned short)0x3F80;
        *(u16x8*)(buf + (quad >> 1) * NKTN * 512 + (2 + (quad & 1)) * 128 + col * 8) = z;
    }
}

// Single-tile 32->16 layer (L7/L8/L9) with preloaded weight frag.
__device__ __forceinline__ void layer_one(bf16x8 af, short* buf, int col, int quad) {
    const int fo = quad * 128 + col * 8;
    bf16x8 b0 = *(const bf16x8*)(buf + fo);
    bf16x8 b1 = *(const bf16x8*)(buf + 512 + fo);
    f32x4 a0 = f32x4{0.f, 0.f, 0.f, 0.f};
    f32x4 a1 = f32x4{0.f, 0.f, 0.f, 0.f};
    a0 = __builtin_amdgcn_mfma_f32_16x16x32_bf16(af, b0, a0, 0, 0, 0);
    a1 = __builtin_amdgcn_mfma_f32_16x16x32_bf16(af, b1, a1, 0, 0, 0);
    const int wbase = (quad >> 1) * 128 + col * 8 + (quad & 1) * 4;
    u32x2 o0, o1;
    o0[0] = pk2(fmaxf(a0[0], 0.f), fmaxf(a0[1], 0.f));
    o0[1] = pk2(fmaxf(a0[2], 0.f), fmaxf(a0[3], 0.f));
    o1[0] = pk2(fmaxf(a1[0], 0.f), fmaxf(a1[1], 0.f));
    o1[1] = pk2(fmaxf(a1[2], 0.f), fmaxf(a1[3], 0.f));
    *(u32x2*)(buf + wbase) = o0;
    *(u32x2*)(buf + 512 + wbase) = o1;
    u16x8 z = {0, 0, 0, 0, 0, 0, 0, 0};
    if ((quad & 1) == 0) z[0] = (unsigned short)0x3F80;
    *(u16x8*)(buf + (quad >> 1) * 512 + (2 + (quad & 1)) * 128 + col * 8) = z;
}

__device__ __forceinline__ float4 ld4(const float* p) {
    float4 t;
    __builtin_memcpy(&t, p, 16);
    return t;
}

// Fetch this wave's two x row-fragments for a chunk into registers.
__device__ __forceinline__ void fetch_x(const float* __restrict__ x, int row0,
                                        int col, int quad, float4& a0, float4& a1) {
    const float* r0 = x + (long)(row0 + col) * 15;
    const float* r1 = x + (long)(row0 + 16 + col) * 15;
    if (quad < 3) {
        a0 = ld4(r0 + quad * 4);
        a1 = ld4(r1 + quad * 4);
    } else {
        // k = 12..14 + bias-col 1.0 at k=15 (load at +11 to stay in bounds)
        float4 t0 = ld4(r0 + 11), t1 = ld4(r1 + 11);
        a0 = make_float4(t0.y, t0.z, t0.w, 1.f);
        a1 = make_float4(t1.y, t1.z, t1.w, 1.f);
    }
}

__device__ __forceinline__ void stage_x(short* buf, float4 a0, float4 a1,
                                        int col, int quad) {
    const int off = (quad >> 1) * 128 + col * 8 + (quad & 1) * 4;
    u32x2 o0, o1;
    o0[0] = pk2(a0.x, a0.y); o0[1] = pk2(a0.z, a0.w);
    o1[0] = pk2(a1.x, a1.y); o1[1] = pk2(a1.z, a1.w);
    *(u32x2*)(buf + off) = o0;
    *(u32x2*)(buf + 512 + off) = o1;
    // k in [16,32): 0 except k==16 := 1.0 (bias_lo column of layer 0)
    u16x8 z = {0, 0, 0, 0, 0, 0, 0, 0};
    if ((quad & 1) == 0) z[0] = (unsigned short)0x3F80;
    *(u16x8*)(buf + (quad >> 1) * 512 + (2 + (quad & 1)) * 128 + col * 8) = z;
}

extern "C" __global__ void __launch_bounds__(512, 2)
mlp_fused(const float* __restrict__ x,
          const float* __restrict__ W0,  const float* __restrict__ B0,
          const float* __restrict__ W1,  const float* __restrict__ B1,
          const float* __restrict__ W2,  const float* __restrict__ B2,
          const float* __restrict__ W3,  const float* __restrict__ B3,
          const float* __restrict__ W4,  const float* __restrict__ B4,
          const float* __restrict__ W5,  const float* __restrict__ B5,
          const float* __restrict__ W6,  const float* __restrict__ B6,
          const float* __restrict__ W7,  const float* __restrict__ B7,
          const float* __restrict__ W8,  const float* __restrict__ B8,
          const float* __restrict__ W9,  const float* __restrict__ B9,
          const float* __restrict__ W10, const float* __restrict__ B10,
          float* __restrict__ out, int nchunks) {
    extern __shared__ short smem[];
    short* wlds = smem;
    short* act  = smem + ACT_OFF;

    const int tid = threadIdx.x;

    stage_w<0>(W0, B0, wlds, tid);
    stage_w<1>(W1, B1, wlds, tid);
    stage_w<2>(W2, B2, wlds, tid);
    stage_w<3>(W3, B3, wlds, tid);
    stage_w<4>(W4, B4, wlds, tid);
    stage_w<5>(W5, B5, wlds, tid);
    stage_w<6>(W6, B6, wlds, tid);
    stage_w<7>(W7, B7, wlds, tid);
    stage_w<8>(W8, B8, wlds, tid);
    stage_w<9>(W9, B9, wlds, tid);
    stage_w<10>(W10, B10, wlds, tid);
    __syncthreads();

    const int wave = tid >> 6;
    const int lane = tid & 63;
    const int col  = lane & 15;
    const int quad = lane >> 4;
    short* buf = act + wave * ARENA;
    const int fo = quad * 128 + col * 8;

    // Tail-layer weight frags live in VGPRs for the whole kernel.
    const bf16x8 w7  = *(const bf16x8*)(wlds + WOFF_[7]  + fo);
    const bf16x8 w8  = *(const bf16x8*)(wlds + WOFF_[8]  + fo);
    const bf16x8 w9  = *(const bf16x8*)(wlds + WOFF_[9]  + fo);
    const bf16x8 w10 = *(const bf16x8*)(wlds + WOFF_[10] + fo);

    int chunk = blockIdx.x;
    float4 xa, xb;
    if (chunk < nchunks)
        fetch_x(x, chunk * ROWS_PER_BLOCK + wave * 32, col, quad, xa, xb);

    for (; chunk < nchunks; chunk += gridDim.x) {
        const int row0 = chunk * ROWS_PER_BLOCK + wave * 32;
        stage_x(buf, xa, xb, col, quad);

        // Prefetch next chunk's x while the layer stack runs.
        const int nxt = chunk + gridDim.x;
        if (nxt < nchunks)
            fetch_x(x, nxt * ROWS_PER_BLOCK + wave * 32, col, quad, xa, xb);

        layer_fwd<0>(wlds, buf, col, quad);
        layer_fwd<1>(wlds, buf, col, quad);
        layer_fwd<2>(wlds, buf, col, quad);
        layer_fwd<3>(wlds, buf, col, quad);
        layer_fwd<4>(wlds, buf, col, quad);
        layer_fwd<5>(wlds, buf, col, quad);
        layer_fwd<6>(wlds, buf, col, quad);
        layer_one(w7, buf, col, quad);
        layer_one(w8, buf, col, quad);
        layer_one(w9, buf, col, quad);

        // Final layer (5 -> 1, bias via pads) + sigmoid.
        {
            bf16x8 b0 = *(const bf16x8*)(buf + fo);
            bf16x8 b1 = *(const bf16x8*)(buf + 512 + fo);
            f32x4 a0 = f32x4{0.f, 0.f, 0.f, 0.f};
            f32x4 a1 = f32x4{0.f, 0.f, 0.f, 0.f};
            a0 = __builtin_amdgcn_mfma_f32_16x16x32_bf16(w10, b0, a0, 0, 0, 0);
            a1 = __builtin_amdgcn_mfma_f32_16x16x32_bf16(w10, b1, a1, 0, 0, 0);
            if (quad == 0) {
                out[row0 + col]      = 1.f / (1.f + __expf(-a0[0]));
                out[row0 + 16 + col] = 1.f / (1.f + __expf(-a1[0]));
            }
        }
    }
}

extern "C" void kernel_launch(void* const* d_in, const int* in_sizes, int n_in,
                              void* d_out, int out_size, void* d_ws, size_t ws_size,
                              hipStream_t stream) {
    (void)n_in; (void)d_ws; (void)ws_size; (void)out_size;
    const float* x = (const float*)d_in[0];
    const float* W[11];
    const float* B[11];
    for (int i = 0; i < 11; ++i) {
        W[i] = (const float*)d_in[1 + 2 * i];
        B[i] = (const float*)d_in[2 + 2 * i];
    }
    const int nrows   = in_sizes[0] / 15;
    const int nchunks = nrows / ROWS_PER_BLOCK;   // 524288/256 = 2048

    hipFuncSetAttribute((const void*)mlp_fused,
                        hipFuncAttributeMaxDynamicSharedMemorySize, LDS_BYTES);

    mlp_fused<<<dim3(256), dim3(512), LDS_BYTES, stream>>>(
        x,
        W[0], B[0], W[1], B[1], W[2], B[2], W[3], B[3], W[4], B[4],
        W[5], B[5], W[6], B[6], W[7], B[7], W[8], B[8], W[9], B[9],
        W[10], B[10],
        (float*)d_out, nchunks);
}